// Round 14
// baseline (716.972 us; speedup 1.0000x reference)
//
#include <hip/hip_runtime.h>
#include <hip/hip_bf16.h>

typedef unsigned int u32;
typedef unsigned short u16;

#define BATCH 256
#define TSTEPS 300
#define N_IN 2312
#define N_H 800
#define N_OUT 10
#define KW 74                  // bitmask words per row (73 data + 1 zero pad)
#define KREAL 2368             // padded real K (= KW*32)
#define KSTEPS 74              // K-steps of 64 k' (= 32 real k = 1 word)
#define MTOT (BATCH * TSTEPS)  // 76800
#define ROWB 9472              // bytes per Wc row (4736 bf16)

#define BM 256
#define BN 80
#define BUFB (BN * 64 * 2)     // 10240 bytes per LDS buffer
#define SRCSTRIDE 75776        // 8 * ROWB (8-row step, swizzle-invariant)

typedef __attribute__((ext_vector_type(8))) short bf16x8;
typedef __attribute__((ext_vector_type(4))) float f32x4;

static inline size_t alignup(size_t x) { return (x + 255) & ~(size_t)255; }

__device__ __forceinline__ void gl_lds16(const void* g, void* l) {
    __builtin_amdgcn_global_load_lds(
        (const __attribute__((address_space(1))) unsigned int*)g,
        (__attribute__((address_space(3))) unsigned int*)l,
        16, 0, 0);
}

// ---------------- w1 -> Wc interleaved (hi,lo) bf16 pairs; block 0 zeroes cnts ----------------
__global__ __launch_bounds__(256) void prep_w(const float* __restrict__ w1,
                                              u32* __restrict__ Wc,
                                              u32* __restrict__ cnts) {
    if (blockIdx.x == 0 && threadIdx.x < 4) cnts[threadIdx.x] = 0;
    int idx = blockIdx.x * 256 + threadIdx.x;
    if (idx >= N_H * KREAL) return;
    int h = idx / KREAL, k = idx - h * KREAL;
    float w = (k < N_IN) ? w1[(size_t)h * N_IN + k] : 0.0f;
    __hip_bfloat16 hb = __float2bfloat16(w);
    float hf = __bfloat162float(hb);
    __hip_bfloat16 lb = __float2bfloat16(w - hf);
    u32 val = (u32)(*(u16*)&hb) | ((u32)(*(u16*)&lb) << 16);
    Wc[(size_t)h * KREAL + k] = val;
}

// ---------------- X (B,N_IN,T) fp32 -> transposed bitmask XBT[w][m], + popcount ----------------
__global__ __launch_bounds__(256) void prep_x(const float* __restrict__ X,
                                              u32* __restrict__ XBT,
                                              u32* __restrict__ cnts,
                                              int b0, int mcount) {
    int bl = blockIdx.x;
    int b = b0 + bl;
    int tc = blockIdx.y;      // 0..4 (t chunks of 64)
    int t0 = tc * 64;
    int nrows = min(64, TSTEPS - t0);
    __shared__ u32 bits[64][76];
    int tid = threadIdx.x;
    int tl = tid & 63;        // local t
    int wg = tid >> 6;        // word group 0..3 (== wave)
    int t = t0 + tl;
    bool tvalid = (tl < nrows);
    u32 pc = 0;
    for (int j = 0; j < 19; ++j) {
        int w = wg + 4 * j;
        if (w >= KW) break;   // uniform per wave
        u32 reg = 0;
        if (tvalid && w < 73) {
            const float* xp = X + ((size_t)b * N_IN + (size_t)w * 32) * TSTEPS + t;
            if (w < 72) {
#pragma unroll
                for (int bit = 0; bit < 32; ++bit) {
                    float v = xp[(size_t)bit * TSTEPS];   // coalesced across lanes (t)
                    reg |= (v > 0.5f) ? (1u << bit) : 0u;
                }
            } else {
#pragma unroll
                for (int bit = 0; bit < 8; ++bit) {       // N_IN = 72*32 + 8
                    float v = xp[(size_t)bit * TSTEPS];
                    reg |= (v > 0.5f) ? (1u << bit) : 0u;
                }
            }
        }
        pc += __popc(reg);
        bits[tl][w] = reg;
    }
    for (int off = 32; off; off >>= 1) pc += __shfl_down(pc, off);
    if ((tid & 63) == 0 && pc) atomicAdd(cnts + 0, pc);
    __syncthreads();
    if (tvalid) {
        int m = bl * TSTEPS + t0 + tl;
        for (int w = wg; w < KW; w += 4)
            XBT[(size_t)w * mcount + m] = bits[tl][w];
    }
}

// ---------------- GEMM: C1[m][h] = sum_k' A'[m][k'] * Wc[h][k'] ----------------
// BN=80: wave tile 64x80, acc[4][5] (80 AGPR) + launch_bounds(256,3) ->
// 3 waves/SIMD, 3 blocks/CU. Barrier/drain head of one block hides under the
// other blocks' MFMA (m114 overlap). 3-buffer counted-vmcnt pipeline.
__global__ __launch_bounds__(256, 3) void gemm_k(const u32* __restrict__ XBT,
                                                 const u16* __restrict__ Wc,
                                                 float* __restrict__ C1,
                                                 int nwg, int mblocks, int mcount) {
    // bijective XCD-chunked swizzle, n-major: consecutive lids share the Wc panel
    int d = blockIdx.y * 10 + blockIdx.x;
    int xcd = d & 7, jj = d >> 3;
    int q = nwg >> 3, r = nwg & 7;
    int lid = (xcd < r ? xcd * (q + 1) : r * (q + 1) + (xcd - r) * q) + jj;
    int nb = lid / mblocks, mb = lid - nb * mblocks;
    int m0 = mb * BM, n0 = nb * BN;

    __shared__ __align__(16) u16 Bs[3][BN * 64];   // 3 x 10 KB

    int tid = threadIdx.x, lane = tid & 63, w = tid >> 6;   // 4 waves, wave tile 64x80

    // B staging base offset: wave w owns rows [w*20, w*20+20).
    // row0 = w*20 + (lane>>3), chunk = lane&7, swizzled; loads i=0,1 full,
    // i=2 lanes<32 (rows +16..19).
    u32 offB;
    {
        int row0 = w * 20 + (lane >> 3);
        offB = (u32)((n0 + row0) * ROWB) + (u32)(((lane & 7) ^ (row0 & 7)) << 4);
    }
    const char* wcBase = (const char*)Wc;
    char* ldsBase = (char*)&Bs[0][0];
    auto STAGE = [&](int sbuf) {
        char* dst = ldsBase + sbuf * BUFB + w * 2560;
        gl_lds16(wcBase + (size_t)offB, dst);
        gl_lds16(wcBase + (size_t)(offB + SRCSTRIDE), dst + 1024);
        if (lane < 32) gl_lds16(wcBase + (size_t)(offB + 2 * SRCSTRIDE), dst + 2048);
        offB += 128;
    };

    // A bitmask: XBT[ks][m0 + w*64 + (lane&15) + 16*mi], mi in [0,4)
    const u32* pA = XBT + m0 + w * 64 + (lane & 15);
    int sh0 = (lane >> 4) * 4;

    f32x4 acc[4][5] = {};

    // prologue: stage(0)->buf0 ; A(0) ; stage(1)->buf1
    STAGE(0);
    u32 a[4];
#pragma unroll
    for (int mi = 0; mi < 4; ++mi) a[mi] = pA[mi * 16];
    pA += mcount;
    STAGE(1);

    int cb = 0, sb = 2;
    for (int ks = 0; ks < KSTEPS; ++ks) {
        // steady state: newest 7 = A(ks)[4] + stage(ks+1)[3]; anything older
        // (incl. stage(ks)) must be complete. Last iter: only A[4] newer.
        if (ks < KSTEPS - 1) asm volatile("s_waitcnt vmcnt(7)" ::: "memory");
        else                 asm volatile("s_waitcnt vmcnt(4)" ::: "memory");
        __builtin_amdgcn_s_barrier();
        asm volatile("" ::: "memory");

        // A(ks+1) register-prefetch, then stage(ks+2)
        u32 an[4];
        if (ks + 1 < KSTEPS) {
#pragma unroll
            for (int mi = 0; mi < 4; ++mi) an[mi] = pA[mi * 16];
            pA += mcount;
        } else {
#pragma unroll
            for (int mi = 0; mi < 4; ++mi) an[mi] = 0;
        }
        if (ks + 2 < KSTEPS) {
            STAGE(sb);
            sb = (sb == 2) ? 0 : sb + 1;
        }

        const u16* bsb = (const u16*)(ldsBase + cb * BUFB);
#pragma unroll
        for (int kk = 0; kk < 2; ++kk) {
            bf16x8 af[4];
#pragma unroll
            for (int mi = 0; mi < 4; ++mi) {
                u32 s = a[mi] >> (kk * 16 + sh0);
                int b0 = ((int)(s << 31)) >> 31;
                int b1 = ((int)(s << 30)) >> 31;
                int b2 = ((int)(s << 29)) >> 31;
                int b3 = ((int)(s << 28)) >> 31;
                uint4 ax;
                ax.x = ((u32)b0) & 0x3F803F80u;
                ax.y = ((u32)b1) & 0x3F803F80u;
                ax.z = ((u32)b2) & 0x3F803F80u;
                ax.w = ((u32)b3) & 0x3F803F80u;
                af[mi] = *reinterpret_cast<bf16x8*>(&ax);
            }
            __builtin_amdgcn_s_setprio(1);
#pragma unroll
            for (int ni = 0; ni < 5; ++ni) {
                int rr = ni * 16 + (lane & 15);
                bf16x8 bf = *reinterpret_cast<const bf16x8*>(
                    &bsb[(rr << 6) + ((((kk << 2) + (lane >> 4)) ^ (rr & 7)) << 3)]);
#pragma unroll
                for (int mi = 0; mi < 4; ++mi)
                    acc[mi][ni] = __builtin_amdgcn_mfma_f32_16x16x32_bf16(af[mi], bf, acc[mi][ni], 0, 0, 0);
            }
            __builtin_amdgcn_s_setprio(0);
        }
#pragma unroll
        for (int mi = 0; mi < 4; ++mi) a[mi] = an[mi];
        cb = (cb == 2) ? 0 : cb + 1;
    }

    // epilogue: C/D layout col=lane&15, row=(lane>>4)*4+j
#pragma unroll
    for (int mi = 0; mi < 4; ++mi)
#pragma unroll
        for (int ni = 0; ni < 5; ++ni) {
            int col = n0 + ni * 16 + (lane & 15);
            int rowb = m0 + w * 64 + mi * 16 + ((lane >> 4) << 2);
#pragma unroll
            for (int j = 0; j < 4; ++j)
                C1[(size_t)(rowb + j) * N_H + col] = acc[mi][ni][j];
        }
}

// ---------------- layer-1: first-spike time per (b,h); 4 h-groups/sample, depth-8 ----------------
__global__ __launch_bounds__(256) void spike1_k(const float* __restrict__ C1,
                                                u16* __restrict__ T1,
                                                u32* __restrict__ cnts,
                                                int b0) {
    const float dm = 0.95122942450071400910f;   // exp(-1/20)
    const float ds = 0.81873075307798185867f;   // exp(-1/5)
    int bl = blockIdx.x, b = b0 + bl, tid = threadIdx.x;
    int h = blockIdx.y * 200 + tid;
    bool act = (tid < 200);
    const float* cp = C1 + (size_t)bl * TSTEPS * N_H + (act ? h : 0);
    float M = 0.0f, S = 0.0f;
    int t1 = TSTEPS;

    float c[8];
#pragma unroll
    for (int r = 0; r < 8; ++r) c[r] = cp[(size_t)r * N_H];
    for (int t = 0; t < TSTEPS; t += 8) {
        float n[8];
#pragma unroll
        for (int r = 0; r < 8; ++r) {
            int tt = t + 8 + r;
            n[r] = (tt < TSTEPS) ? cp[(size_t)tt * N_H] : 0.0f;
        }
#pragma unroll
        for (int r = 0; r < 8; ++r) {
            M = dm * M + c[r];
            S = ds * S + c[r];
            if (M - S > 1.0f && t + r < t1) t1 = t + r;
        }
#pragma unroll
        for (int r = 0; r < 8; ++r) c[r] = n[r];
    }

    if (act) T1[(size_t)b * N_H + h] = (u16)t1;
    u32 cnt = (act && t1 < TSTEPS) ? 1u : 0u;
    for (int off = 32; off; off >>= 1) cnt += __shfl_down(cnt, off);
    if ((tid & 63) == 0 && cnt) atomicAdd(cnts + 1, cnt);
}

// ---------------- layer-2: wave-parallel deterministic gather + 10-lane recursion ----------------
__global__ __launch_bounds__(320) void out_k(const u16* __restrict__ T1,
                                             const float* __restrict__ w2,
                                             float* __restrict__ out,
                                             u32* __restrict__ cnts) {
    const float dm = 0.95122942450071400910f;
    const float ds = 0.81873075307798185867f;
    int b = blockIdx.x, tid = threadIdx.x;
    __shared__ float w2s[N_OUT * N_H];   // 32 KB
    __shared__ u16 t1s[N_H];
    __shared__ float Rs[TSTEPS][N_OUT];  // 12 KB
    for (int i = tid; i < N_OUT * N_H; i += 320) w2s[i] = w2[i];
    for (int i = tid; i < N_H; i += 320) t1s[i] = T1[(size_t)b * N_H + i];
    __syncthreads();

    int t = (tid < TSTEPS) ? tid : -1;
    float R[N_OUT];
#pragma unroll
    for (int o = 0; o < N_OUT; ++o) R[o] = 0.0f;
    for (int h = 0; h < N_H; ++h) {
        int th = t1s[h];
        if (th == t) {
#pragma unroll
            for (int o = 0; o < N_OUT; ++o) R[o] += w2s[o * N_H + h];
        }
    }
    if (t >= 0) {
#pragma unroll
        for (int o = 0; o < N_OUT; ++o) Rs[t][o] = R[o];
    }
    __syncthreads();

    if (tid < N_OUT) {
        float vm = 0.0f, vs = 0.0f, sav = 1.0f, ot = (float)TSTEPS, ou = 0.0f;
        u32 c2 = 0;
        for (int tt = 0; tt < TSTEPS; ++tt) {
            float rr = Rs[tt][tid];
            vm = dm * vm + rr;
            vs = ds * vs + rr;
            float u2 = sav * (vm - vs);
            float spk = (u2 - 1.0f > 0.0f) ? 1.0f : 0.0f;
            sav *= (1.0f - spk);
            ot += spk * ((float)tt - (float)TSTEPS);
            ou += spk * u2;
            c2 += (u32)spk;
        }
        out[b * N_OUT + tid] = ot;
        out[BATCH * N_OUT + b * N_OUT + tid] = ou;
        if (c2) atomicAdd(cnts + 2, c2);
    }
}

// ---------------- finalize sum_sp ----------------
__global__ void fin_k(const u32* cnts, float* out) {
    if (threadIdx.x == 0) {
        out[2 * BATCH * N_OUT + 0] = (float)cnts[0];
        out[2 * BATCH * N_OUT + 1] = (float)cnts[1];
        out[2 * BATCH * N_OUT + 2] = (float)cnts[2];
    }
}

extern "C" void kernel_launch(void* const* d_in, const int* in_sizes, int n_in,
                              void* d_out, int out_size, void* d_ws, size_t ws_size,
                              hipStream_t stream) {
    (void)in_sizes; (void)n_in; (void)out_size;
    const float* X  = (const float*)d_in[0];
    const float* w1 = (const float*)d_in[1];
    const float* w2 = (const float*)d_in[2];
    float* out = (float*)d_out;
    char* ws = (char*)d_ws;

    const size_t WC_BYTES = (size_t)N_H * KREAL * 4;  // 7.58 MB
    const size_t T1_BYTES = (size_t)BATCH * N_H * 2;  // 410 KB

    // choose batch chunking so XBT + C1 fit in workspace (mcount must be /256)
    int nch = 1;
    for (; nch <= 4; nch *= 2) {
        size_t xbb = (size_t)(MTOT / nch) * KW * 4;
        size_t c1b = (size_t)(MTOT / nch) * N_H * 4;
        size_t tot = alignup(xbb) + alignup(c1b) + alignup(WC_BYTES) + alignup(T1_BYTES) + 256;
        if (tot <= ws_size) break;
    }
    if (nch > 4) nch = 4;
    int bchunk = BATCH / nch;
    int mcount = bchunk * TSTEPS;
    int mblocks = mcount / BM;
    int nwg = 10 * mblocks;

    size_t off = 0;
    u32* XBT  = (u32*)(ws + off);   off += alignup((size_t)mcount * KW * 4);
    float* C1 = (float*)(ws + off); off += alignup((size_t)mcount * N_H * 4);
    u32* Wc   = (u32*)(ws + off);   off += alignup(WC_BYTES);
    u16* T1   = (u16*)(ws + off);   off += alignup(T1_BYTES);
    u32* cnts = (u32*)(ws + off);

    prep_w<<<(N_H * KREAL) / 256, 256, 0, stream>>>(w1, Wc, cnts);

    for (int c = 0; c < nch; ++c) {
        int b0 = c * bchunk;
        prep_x<<<dim3(bchunk, 5), 256, 0, stream>>>(X, XBT, cnts, b0, mcount);
        gemm_k<<<dim3(10, mblocks), 256, 0, stream>>>(XBT, (const u16*)Wc, C1, nwg, mblocks, mcount);
        spike1_k<<<dim3(bchunk, 4), 256, 0, stream>>>(C1, T1, cnts, b0);
    }
    out_k<<<BATCH, 320, 0, stream>>>(T1, w2, out, cnts);
    fin_k<<<1, 64, 0, stream>>>(cnts, out);
}

// Round 15
// 708.927 us; speedup vs baseline: 1.0113x; 1.0113x over previous
//
#include <hip/hip_runtime.h>
#include <hip/hip_bf16.h>

typedef unsigned int u32;
typedef unsigned short u16;

#define BATCH 256
#define TSTEPS 300
#define N_IN 2312
#define N_H 800
#define N_OUT 10
#define KW 74                  // bitmask words per row (73 data + 1 zero pad)
#define KREAL 2368             // padded real K (= KW*32)
#define KSTEPS 74              // K-steps of 64 k' (= 32 real k = 1 word)
#define MTOT (BATCH * TSTEPS)  // 76800
#define ROWB 9472              // bytes per Wc row (4736 bf16)

#define BM 256
#define BN 160
#define BUFB (BN * 64 * 2)     // 20480 bytes per LDS buffer
#define SRCSTRIDE 75776        // 8 * ROWB: srcB[i+1] - srcB[i] (swizzle-invariant)

typedef __attribute__((ext_vector_type(8))) short bf16x8;
typedef __attribute__((ext_vector_type(4))) float f32x4;

static inline size_t alignup(size_t x) { return (x + 255) & ~(size_t)255; }

__device__ __forceinline__ void gl_lds16(const void* g, void* l) {
    __builtin_amdgcn_global_load_lds(
        (const __attribute__((address_space(1))) unsigned int*)g,
        (__attribute__((address_space(3))) unsigned int*)l,
        16, 0, 0);
}

// ---------------- w1 -> Wc interleaved (hi,lo) bf16 pairs; block 0 zeroes cnts ----------------
__global__ __launch_bounds__(256) void prep_w(const float* __restrict__ w1,
                                              u32* __restrict__ Wc,
                                              u32* __restrict__ cnts) {
    if (blockIdx.x == 0 && threadIdx.x < 4) cnts[threadIdx.x] = 0;
    int idx = blockIdx.x * 256 + threadIdx.x;
    if (idx >= N_H * KREAL) return;
    int h = idx / KREAL, k = idx - h * KREAL;
    float w = (k < N_IN) ? w1[(size_t)h * N_IN + k] : 0.0f;
    __hip_bfloat16 hb = __float2bfloat16(w);
    float hf = __bfloat162float(hb);
    __hip_bfloat16 lb = __float2bfloat16(w - hf);
    u32 val = (u32)(*(u16*)&hb) | ((u32)(*(u16*)&lb) << 16);
    Wc[(size_t)h * KREAL + k] = val;
}

// ---------------- X (B,N_IN,T) fp32 -> transposed bitmask XBT[w][m], + popcount ----------------
__global__ __launch_bounds__(256) void prep_x(const float* __restrict__ X,
                                              u32* __restrict__ XBT,
                                              u32* __restrict__ cnts,
                                              int b0, int mcount) {
    int bl = blockIdx.x;
    int b = b0 + bl;
    int tc = blockIdx.y;      // 0..4 (t chunks of 64)
    int t0 = tc * 64;
    int nrows = min(64, TSTEPS - t0);
    __shared__ u32 bits[64][76];
    int tid = threadIdx.x;
    int tl = tid & 63;        // local t
    int wg = tid >> 6;        // word group 0..3 (== wave)
    int t = t0 + tl;
    bool tvalid = (tl < nrows);
    u32 pc = 0;
    for (int j = 0; j < 19; ++j) {
        int w = wg + 4 * j;
        if (w >= KW) break;   // uniform per wave
        u32 reg = 0;
        if (tvalid && w < 73) {
            const float* xp = X + ((size_t)b * N_IN + (size_t)w * 32) * TSTEPS + t;
            if (w < 72) {
#pragma unroll
                for (int bit = 0; bit < 32; ++bit) {
                    float v = xp[(size_t)bit * TSTEPS];   // coalesced across lanes (t)
                    reg |= (v > 0.5f) ? (1u << bit) : 0u;
                }
            } else {
#pragma unroll
                for (int bit = 0; bit < 8; ++bit) {       // N_IN = 72*32 + 8
                    float v = xp[(size_t)bit * TSTEPS];
                    reg |= (v > 0.5f) ? (1u << bit) : 0u;
                }
            }
        }
        pc += __popc(reg);
        bits[tl][w] = reg;
    }
    for (int off = 32; off; off >>= 1) pc += __shfl_down(pc, off);
    if ((tid & 63) == 0 && pc) atomicAdd(cnts + 0, pc);
    __syncthreads();
    if (tvalid) {
        int m = bl * TSTEPS + t0 + tl;
        for (int w = wg; w < KW; w += 4)
            XBT[(size_t)w * mcount + m] = bits[tl][w];
    }
}

// ---------------- GEMM: C1[m][h] = sum_k' A'[m][k'] * Wc[h][k'] ----------------
// r13 configuration (measured optimum): N-heavy wave tile 64x160, 16x16x32
// MFMA, acc[4][10], 3-buffer single-barrier counted-vmcnt pipeline, B-staging
// collapsed to one 32-bit offset.
__global__ __launch_bounds__(256, 2) void gemm_k(const u32* __restrict__ XBT,
                                                 const u16* __restrict__ Wc,
                                                 float* __restrict__ C1,
                                                 int nwg, int mblocks, int mcount) {
    // bijective XCD-chunked swizzle, n-major: consecutive lids share the Wc panel
    int d = blockIdx.y * 5 + blockIdx.x;
    int xcd = d & 7, jj = d >> 3;
    int q = nwg >> 3, r = nwg & 7;
    int lid = (xcd < r ? xcd * (q + 1) : r * (q + 1) + (xcd - r) * q) + jj;
    int nb = lid / mblocks, mb = lid - nb * mblocks;
    int m0 = mb * BM, n0 = nb * BN;

    __shared__ __align__(16) u16 Bs[3][BN * 64];   // 3 x 20 KB

    int tid = threadIdx.x, lane = tid & 63, w = tid >> 6;   // 4 waves, wave tile 64x160

    // B staging base offset (bytes into Wc) for this lane's first 16B chunk:
    // row0 = w*40 + (lane>>3), col chunk c = lane&7, swizzle c ^ (row0&7)
    u32 offB;
    {
        int row0 = w * 40 + (lane >> 3);
        offB = (u32)((n0 + row0) * ROWB) + (u32)(((lane & 7) ^ (row0 & 7)) << 4);
    }
    const char* wcBase = (const char*)Wc;
    char* ldsBase = (char*)&Bs[0][0];
    auto STAGE = [&](int sbuf) {
        char* dst = ldsBase + sbuf * BUFB + w * 5120;
#pragma unroll
        for (int i = 0; i < 5; ++i)
            gl_lds16(wcBase + (size_t)(offB + (u32)(i * SRCSTRIDE)), dst + i * 1024);
        offB += 128;
    };

    // A bitmask: XBT[ks][m0 + w*64 + (lane&15) + 16*mi], mi in [0,4)
    const u32* pA = XBT + m0 + w * 64 + (lane & 15);
    int sh0 = (lane >> 4) * 4;

    f32x4 acc[4][10] = {};

    // prologue: stage(0)->buf0 ; A(0) ; stage(1)->buf1
    STAGE(0);
    u32 a[4];
#pragma unroll
    for (int mi = 0; mi < 4; ++mi) a[mi] = pA[mi * 16];
    pA += mcount;
    STAGE(1);

    int cb = 0, sb = 2;
    for (int ks = 0; ks < KSTEPS; ++ks) {
        // steady state: newest 9 = A(ks)[4] + stage(ks+1)[5]; anything older
        // (incl. stage(ks)) must be complete. Last iter: only A[4] newer.
        if (ks < KSTEPS - 1) asm volatile("s_waitcnt vmcnt(9)" ::: "memory");
        else                 asm volatile("s_waitcnt vmcnt(4)" ::: "memory");
        __builtin_amdgcn_s_barrier();
        asm volatile("" ::: "memory");

        // A(ks+1) register-prefetch, then stage(ks+2)
        u32 an[4];
        if (ks + 1 < KSTEPS) {
#pragma unroll
            for (int mi = 0; mi < 4; ++mi) an[mi] = pA[mi * 16];
            pA += mcount;
        } else {
#pragma unroll
            for (int mi = 0; mi < 4; ++mi) an[mi] = 0;
        }
        if (ks + 2 < KSTEPS) {
            STAGE(sb);
            sb = (sb == 2) ? 0 : sb + 1;
        }

        const u16* bsb = (const u16*)(ldsBase + cb * BUFB);
#pragma unroll
        for (int kk = 0; kk < 2; ++kk) {
            bf16x8 af[4];
#pragma unroll
            for (int mi = 0; mi < 4; ++mi) {
                u32 s = a[mi] >> (kk * 16 + sh0);
                int b0 = ((int)(s << 31)) >> 31;
                int b1 = ((int)(s << 30)) >> 31;
                int b2 = ((int)(s << 29)) >> 31;
                int b3 = ((int)(s << 28)) >> 31;
                uint4 ax;
                ax.x = ((u32)b0) & 0x3F803F80u;
                ax.y = ((u32)b1) & 0x3F803F80u;
                ax.z = ((u32)b2) & 0x3F803F80u;
                ax.w = ((u32)b3) & 0x3F803F80u;
                af[mi] = *reinterpret_cast<bf16x8*>(&ax);
            }
            __builtin_amdgcn_s_setprio(1);
#pragma unroll
            for (int ni = 0; ni < 10; ++ni) {
                int rr = ni * 16 + (lane & 15);
                bf16x8 bf = *reinterpret_cast<const bf16x8*>(
                    &bsb[(rr << 6) + ((((kk << 2) + (lane >> 4)) ^ (rr & 7)) << 3)]);
#pragma unroll
                for (int mi = 0; mi < 4; ++mi)
                    acc[mi][ni] = __builtin_amdgcn_mfma_f32_16x16x32_bf16(af[mi], bf, acc[mi][ni], 0, 0, 0);
            }
            __builtin_amdgcn_s_setprio(0);
        }
#pragma unroll
        for (int mi = 0; mi < 4; ++mi) a[mi] = an[mi];
        cb = (cb == 2) ? 0 : cb + 1;
    }

    // epilogue: C/D layout col=lane&15, row=(lane>>4)*4+j
#pragma unroll
    for (int mi = 0; mi < 4; ++mi)
#pragma unroll
        for (int ni = 0; ni < 10; ++ni) {
            int col = n0 + ni * 16 + (lane & 15);
            int rowb = m0 + w * 64 + mi * 16 + ((lane >> 4) << 2);
#pragma unroll
            for (int j = 0; j < 4; ++j)
                C1[(size_t)(rowb + j) * N_H + col] = acc[mi][ni][j];
        }
}

// ---------------- layer-1: first-spike time per (b,h); 4 h-groups/sample, depth-8 ----------------
__global__ __launch_bounds__(256) void spike1_k(const float* __restrict__ C1,
                                                u16* __restrict__ T1,
                                                u32* __restrict__ cnts,
                                                int b0) {
    const float dm = 0.95122942450071400910f;   // exp(-1/20)
    const float ds = 0.81873075307798185867f;   // exp(-1/5)
    int bl = blockIdx.x, b = b0 + bl, tid = threadIdx.x;
    int h = blockIdx.y * 200 + tid;
    bool act = (tid < 200);
    const float* cp = C1 + (size_t)bl * TSTEPS * N_H + (act ? h : 0);
    float M = 0.0f, S = 0.0f;
    int t1 = TSTEPS;

    float c[8];
#pragma unroll
    for (int r = 0; r < 8; ++r) c[r] = cp[(size_t)r * N_H];
    for (int t = 0; t < TSTEPS; t += 8) {
        float n[8];
#pragma unroll
        for (int r = 0; r < 8; ++r) {
            int tt = t + 8 + r;
            n[r] = (tt < TSTEPS) ? cp[(size_t)tt * N_H] : 0.0f;
        }
#pragma unroll
        for (int r = 0; r < 8; ++r) {
            M = dm * M + c[r];
            S = ds * S + c[r];
            if (M - S > 1.0f && t + r < t1) t1 = t + r;
        }
#pragma unroll
        for (int r = 0; r < 8; ++r) c[r] = n[r];
    }

    if (act) T1[(size_t)b * N_H + h] = (u16)t1;
    u32 cnt = (act && t1 < TSTEPS) ? 1u : 0u;
    for (int off = 32; off; off >>= 1) cnt += __shfl_down(cnt, off);
    if ((tid & 63) == 0 && cnt) atomicAdd(cnts + 1, cnt);
}

// ---------------- layer-2: wave-parallel deterministic gather + 10-lane recursion ----------------
__global__ __launch_bounds__(320) void out_k(const u16* __restrict__ T1,
                                             const float* __restrict__ w2,
                                             float* __restrict__ out,
                                             u32* __restrict__ cnts) {
    const float dm = 0.95122942450071400910f;
    const float ds = 0.81873075307798185867f;
    int b = blockIdx.x, tid = threadIdx.x;
    __shared__ float w2s[N_OUT * N_H];   // 32 KB
    __shared__ u16 t1s[N_H];
    __shared__ float Rs[TSTEPS][N_OUT];  // 12 KB
    for (int i = tid; i < N_OUT * N_H; i += 320) w2s[i] = w2[i];
    for (int i = tid; i < N_H; i += 320) t1s[i] = T1[(size_t)b * N_H + i];
    __syncthreads();

    int t = (tid < TSTEPS) ? tid : -1;
    float R[N_OUT];
#pragma unroll
    for (int o = 0; o < N_OUT; ++o) R[o] = 0.0f;
    for (int h = 0; h < N_H; ++h) {
        int th = t1s[h];
        if (th == t) {
#pragma unroll
            for (int o = 0; o < N_OUT; ++o) R[o] += w2s[o * N_H + h];
        }
    }
    if (t >= 0) {
#pragma unroll
        for (int o = 0; o < N_OUT; ++o) Rs[t][o] = R[o];
    }
    __syncthreads();

    if (tid < N_OUT) {
        float vm = 0.0f, vs = 0.0f, sav = 1.0f, ot = (float)TSTEPS, ou = 0.0f;
        u32 c2 = 0;
        for (int tt = 0; tt < TSTEPS; ++tt) {
            float rr = Rs[tt][tid];
            vm = dm * vm + rr;
            vs = ds * vs + rr;
            float u2 = sav * (vm - vs);
            float spk = (u2 - 1.0f > 0.0f) ? 1.0f : 0.0f;
            sav *= (1.0f - spk);
            ot += spk * ((float)tt - (float)TSTEPS);
            ou += spk * u2;
            c2 += (u32)spk;
        }
        out[b * N_OUT + tid] = ot;
        out[BATCH * N_OUT + b * N_OUT + tid] = ou;
        if (c2) atomicAdd(cnts + 2, c2);
    }
}

// ---------------- finalize sum_sp ----------------
__global__ void fin_k(const u32* cnts, float* out) {
    if (threadIdx.x == 0) {
        out[2 * BATCH * N_OUT + 0] = (float)cnts[0];
        out[2 * BATCH * N_OUT + 1] = (float)cnts[1];
        out[2 * BATCH * N_OUT + 2] = (float)cnts[2];
    }
}

extern "C" void kernel_launch(void* const* d_in, const int* in_sizes, int n_in,
                              void* d_out, int out_size, void* d_ws, size_t ws_size,
                              hipStream_t stream) {
    (void)in_sizes; (void)n_in; (void)out_size;
    const float* X  = (const float*)d_in[0];
    const float* w1 = (const float*)d_in[1];
    const float* w2 = (const float*)d_in[2];
    float* out = (float*)d_out;
    char* ws = (char*)d_ws;

    const size_t WC_BYTES = (size_t)N_H * KREAL * 4;  // 7.58 MB
    const size_t T1_BYTES = (size_t)BATCH * N_H * 2;  // 410 KB

    // choose batch chunking so XBT + C1 fit in workspace (mcount must be /256)
    int nch = 1;
    for (; nch <= 4; nch *= 2) {
        size_t xbb = (size_t)(MTOT / nch) * KW * 4;
        size_t c1b = (size_t)(MTOT / nch) * N_H * 4;
        size_t tot = alignup(xbb) + alignup(c1b) + alignup(WC_BYTES) + alignup(T1_BYTES) + 256;
        if (tot <= ws_size) break;
    }
    if (nch > 4) nch = 4;
    int bchunk = BATCH / nch;
    int mcount = bchunk * TSTEPS;
    int mblocks = mcount / BM;
    int nwg = 5 * mblocks;

    size_t off = 0;
    u32* XBT  = (u32*)(ws + off);   off += alignup((size_t)mcount * KW * 4);
    float* C1 = (float*)(ws + off); off += alignup((size_t)mcount * N_H * 4);
    u32* Wc   = (u32*)(ws + off);   off += alignup(WC_BYTES);
    u16* T1   = (u16*)(ws + off);   off += alignup(T1_BYTES);
    u32* cnts = (u32*)(ws + off);

    prep_w<<<(N_H * KREAL) / 256, 256, 0, stream>>>(w1, Wc, cnts);

    for (int c = 0; c < nch; ++c) {
        int b0 = c * bchunk;
        prep_x<<<dim3(bchunk, 5), 256, 0, stream>>>(X, XBT, cnts, b0, mcount);
        gemm_k<<<dim3(5, mblocks), 256, 0, stream>>>(XBT, (const u16*)Wc, C1, nwg, mblocks, mcount);
        spike1_k<<<dim3(bchunk, 4), 256, 0, stream>>>(C1, T1, cnts, b0);
    }
    out_k<<<BATCH, 320, 0, stream>>>(T1, w2, out, cnts);
    fin_k<<<1, 64, 0, stream>>>(cnts, out);
}